// Round 16
// baseline (278.709 us; speedup 1.0000x reference)
//
#include <hip/hip_runtime.h>
#include <cstddef>

#define B_    32
#define N_    1024
#define E_    4096
#define A_    16
#define FIN_  16
#define H_    64
#define MID_  208
#define NODES (B_ * N_)      // 32768
#define NEDGE (B_ * E_)      // 131072
#define ROWS  (B_ * A_ * N_) // 524288
#define AN_   (A_ * N_)      // 16384

__device__ __forceinline__ float readlane_f(float v, int l) {
  return __uint_as_float(__builtin_amdgcn_readlane(__float_as_uint(v), l));
}

// ---------------- front: per-graph CSR in-block (LDS-staged ssrc) + d1 + csum + cu ----------------
__global__ __launch_bounds__(256) void k_front(const int* __restrict__ el,
                                               const float* __restrict__ dist,
                                               const int* __restrict__ loc,
                                               const float* __restrict__ W1,
                                               const float* __restrict__ eW,
                                               const float* __restrict__ eb,
                                               const float* __restrict__ b1,
                                               int* __restrict__ rowptr,
                                               int* __restrict__ counts,
                                               int* __restrict__ ssrc,
                                               float* __restrict__ d1row,
                                               float* __restrict__ c2row,
                                               float* __restrict__ e1,
                                               float* __restrict__ cu,
                                               float* __restrict__ base) {
  __shared__ int cnt[1024];
  __shared__ int cur[1024];
  __shared__ int part[256];
  __shared__ int ssrcS[4096];
  __shared__ int loc_s[16];
  int blk = blockIdx.x, t = threadIdx.x;
  if (blk < 32) {
    int b = blk;
    for (int i = t; i < 1024; i += 256) cnt[i] = 0;
    __syncthreads();
    const int* srcp = el + b * (2 * E_);
    const int* dstp = srcp + E_;
    for (int i = t; i < E_; i += 256) atomicAdd(&cnt[dstp[i]], 1);
    __syncthreads();
    int4 c4 = *(const int4*)&cnt[t * 4];
    int s = c4.x + c4.y + c4.z + c4.w;
    part[t] = s;
    __syncthreads();
    for (int off = 1; off < 256; off <<= 1) {
      int v = (t >= off) ? part[t - off] : 0;
      __syncthreads();
      part[t] += v;
      __syncthreads();
    }
    int prev = (t == 0) ? 0 : part[t - 1];
    int p0 = prev, p1 = p0 + c4.x, p2 = p1 + c4.y, p3 = p2 + c4.z;
    *(int4*)&rowptr[b * 1024 + t * 4] = make_int4(p0 + b * E_, p1 + b * E_, p2 + b * E_, p3 + b * E_);
    *(int4*)&counts[b * 1024 + t * 4] = c4;
    cur[t * 4 + 0] = p0;
    cur[t * 4 + 1] = p1;
    cur[t * 4 + 2] = p2;
    cur[t * 4 + 3] = p3;
    __syncthreads();
    for (int i = t; i < E_; i += 256) {
      int dl = dstp[i];
      int sl = srcp[i];
      int pos = atomicAdd(&cur[dl], 1);
      ssrcS[pos] = b * N_ + sl;
    }
    __syncthreads();
    for (int i = t; i < E_; i += 256) ssrc[b * E_ + i] = ssrcS[i];
  } else if (blk < 288) {
    int lane = t & 63, w = t >> 6;
    int r = (blk - 32) * 4 + w;
    const float* dr = dist + (size_t)r * N_;
    float s = 0.f, c2 = 0.f;
#pragma unroll
    for (int k = 0; k < 16; k++) {
      float v = dr[lane + 64 * k];
      s += v;
      c2 = fmaf(v, v, c2);
    }
#pragma unroll
    for (int o = 32; o > 0; o >>= 1) { s += __shfl_xor(s, o); c2 += __shfl_xor(c2, o); }
    if (lane == 0) { d1row[r] = s; c2row[r] = c2; }
  } else if (blk < 320) {
    int b = blk - 288;
    if (t < 16) loc_s[t] = loc[b * 16 + t];
    __syncthreads();
    float e4[4] = {0.f, 0.f, 0.f, 0.f};
    for (int a = 0; a < 16; a++) {
      const float* dr = dist + (size_t)loc_s[a] * N_;
#pragma unroll
      for (int k = 0; k < 4; k++) e4[k] += dr[t + 256 * k];
    }
#pragma unroll
    for (int k = 0; k < 4; k++) e1[b * N_ + t + 256 * k] = e4[k];
  } else {
    int j = t;
    if (j < MID_) {
      float c = 0.f, bs = 0.f;
      for (int k = 0; k < H_; k++) {
        float w = W1[(2 * MID_ + k) * MID_ + j];
        c = fmaf(eW[k], w, c);
        bs = fmaf(eb[k], w, bs);
      }
      cu[j] = c;
      base[j] = bs + b1[j];
    }
  }
}

// ---------------- GIN layer: wave per 8 nodes; deep-MLP gather, then matvec ----------------
template <int FINT, bool COPYIN>
__global__ __launch_bounds__(256) void k_layer(const float* __restrict__ xin, int xstride, int in_off,
                                               float* __restrict__ xc, int out_off,
                                               const int* __restrict__ rowptr,
                                               const int* __restrict__ counts,
                                               const int* __restrict__ ssrc,
                                               const float* __restrict__ W,
                                               const float* __restrict__ bias,
                                               const float* __restrict__ g,
                                               const float* __restrict__ beta) {
  int t = threadIdx.x, lane = t & 63, w = t >> 6;
  float Wcol[FINT];
#pragma unroll
  for (int f = 0; f < FINT; f++) Wcol[f] = W[f * 64 + lane];
  float bv = bias[lane], gv = g[lane], bev = beta[lane];
  constexpr int CH = 64 / FINT;
  int f = lane & (FINT - 1);
  int ch = (FINT == 64) ? 0 : (lane >> 4);
  int nbase = (blockIdx.x * 4 + w) * 8;

  float agg[8];
#pragma unroll
  for (int nn = 0; nn < 8; nn++) {
    int node = nbase + nn;
    int r0 = rowptr[node];
    int deg = counts[node];
    float a0 = 0.f, a1 = 0.f, a2 = 0.f, a3 = 0.f;
    int e = ch;
    for (; e + 3 * CH < deg; e += 4 * CH) {
      int s0 = ssrc[r0 + e];
      int s1 = ssrc[r0 + e + CH];
      int s2 = ssrc[r0 + e + 2 * CH];
      int s3 = ssrc[r0 + e + 3 * CH];
      a0 += xin[(size_t)s0 * xstride + in_off + f];
      a1 += xin[(size_t)s1 * xstride + in_off + f];
      a2 += xin[(size_t)s2 * xstride + in_off + f];
      a3 += xin[(size_t)s3 * xstride + in_off + f];
    }
    for (; e < deg; e += CH) {
      int s = ssrc[r0 + e];
      a0 += xin[(size_t)s * xstride + in_off + f];
    }
    agg[nn] = (a0 + a1) + (a2 + a3);
  }

#pragma unroll
  for (int nn = 0; nn < 8; nn++) {
    int node = nbase + nn;
    float aggf = agg[nn];
    float y0 = bv, y1 = 0.f, y2 = 0.f, y3 = 0.f;
#pragma unroll
    for (int l = 0; l < 64; l += 4) {
      y0 = fmaf(readlane_f(aggf, l + 0), Wcol[(l + 0) & (FINT - 1)], y0);
      y1 = fmaf(readlane_f(aggf, l + 1), Wcol[(l + 1) & (FINT - 1)], y1);
      y2 = fmaf(readlane_f(aggf, l + 2), Wcol[(l + 2) & (FINT - 1)], y2);
      y3 = fmaf(readlane_f(aggf, l + 3), Wcol[(l + 3) & (FINT - 1)], y3);
    }
    float y = (y0 + y1) + (y2 + y3);
    float m = y;
#pragma unroll
    for (int o = 32; o > 0; o >>= 1) m += __shfl_xor(m, o);
    m *= (1.f / 64.f);
    float d = y - m;
    float vv = d * d;
#pragma unroll
    for (int o = 32; o > 0; o >>= 1) vv += __shfl_xor(vv, o);
    vv *= (1.f / 64.f);
    float outv = fmaxf(d * rsqrtf(vv + 1e-5f) * gv + bev, 0.f);
    xc[(size_t)node * MID_ + out_off + lane] = outv;
    if (COPYIN) {
      if (lane < FIN_) xc[(size_t)node * MID_ + lane] = xin[(size_t)node * FIN_ + lane];
    }
  }
}

// ---------------- LDS-free scalar-A GEMM core: wave = NR rows, lane = 4 j ----------------
template <int NR>
__device__ __forceinline__ void gemm_sc(const float* __restrict__ xc,
                                        const float* __restrict__ W1,
                                        int row0w, int j0, float acc[NR][4]) {
  const float* Bbase = W1 + (size_t)MID_ * MID_;
  const float* Arow = xc + (size_t)row0w * MID_;
#pragma unroll
  for (int r = 0; r < NR; r++)
#pragma unroll
    for (int q = 0; q < 4; q++) acc[r][q] = 0.f;

#pragma unroll 2
  for (int c = 0; c < 52; c++) {
    int k = c * 4;
    float4 a[NR];
    const float* ap = Arow + k;
#pragma unroll
    for (int r = 0; r < NR; r++) a[r] = *(const float4*)(ap + r * MID_);
#pragma unroll
    for (int q = 0; q < 4; q++) {
      float4 bq = *(const float4*)(Bbase + (size_t)(k + q) * MID_ + j0);
#pragma unroll
      for (int r = 0; r < NR; r++) {
        float ar = (q == 0) ? a[r].x : (q == 1) ? a[r].y : (q == 2) ? a[r].z : a[r].w;
        acc[r][0] = fmaf(ar, bq.x, acc[r][0]);
        acc[r][1] = fmaf(ar, bq.y, acc[r][1]);
        acc[r][2] = fmaf(ar, bq.z, acc[r][2]);
        acc[r][3] = fmaf(ar, bq.w, acc[r][3]);
      }
    }
  }
}

// ---------------- p1: 128-thread blocks. 0..2047: GEMM (2 waves x 8 rows) + stats + pBT; 2048..2559: pA ----------------
#define TSTR 105
__global__ __launch_bounds__(128) void k_p1(const float* __restrict__ xc,
                                            const float* __restrict__ W1,
                                            const float* __restrict__ e1,
                                            const int* __restrict__ loc,
                                            float* __restrict__ SBp,
                                            float* __restrict__ pBT,
                                            float* __restrict__ pA) {
  __shared__ float smem[1680];   // union: red[2*624] / accS[16*105] / xr[208]
  int t = threadIdx.x, lane = t & 63;
  int w = __builtin_amdgcn_readfirstlane(t >> 6);   // 0 or 1
  int blk = blockIdx.x;
  if (blk < 2048) {
    int row0 = blk * 16;
    int row0w = row0 + w * 8;
    int j0 = lane * 4;
    float acc[8][4];
    gemm_sc<8>(xc, W1, row0w, j0, acc);
    const float* ep = e1 + row0w;   // wave-uniform
    float4 e0 = *(const float4*)(ep);
    float4 e4 = *(const float4*)(ep + 4);
    float ev[8] = {e0.x, e0.y, e0.z, e0.w, e4.x, e4.y, e4.z, e4.w};
    if (j0 < MID_) {
      float s1[4] = {0, 0, 0, 0}, s2[4] = {0, 0, 0, 0}, se[4] = {0, 0, 0, 0};
#pragma unroll
      for (int r = 0; r < 8; r++) {
#pragma unroll
        for (int q = 0; q < 4; q++) {
          float v = acc[r][q];
          s1[q] += v;
          s2[q] = fmaf(v, v, s2[q]);
          se[q] = fmaf(v, ev[r], se[q]);
        }
      }
#pragma unroll
      for (int q = 0; q < 4; q++) {
        smem[w * 624 + j0 + q] = s1[q];
        smem[w * 624 + 208 + j0 + q] = s2[q];
        smem[w * 624 + 416 + j0 + q] = se[q];
      }
    }
    __syncthreads();
    for (int idx = t; idx < 624; idx += 128) {
      SBp[(size_t)blk * 624 + idx] = smem[idx] + smem[624 + idx];
    }
    // transpose acc -> pBT via 2-half LDS staging (smem reused as accS[16][105])
#pragma unroll
    for (int half = 0; half < 2; half++) {
      int lo = half * 104;
      __syncthreads();
      if (j0 >= lo && j0 < lo + 104) {
        int jc = j0 - lo;
#pragma unroll
        for (int r = 0; r < 8; r++) {
          int ba = (w * 8 + r) * TSTR + jc;
          smem[ba + 0] = acc[r][0];
          smem[ba + 1] = acc[r][1];
          smem[ba + 2] = acc[r][2];
          smem[ba + 3] = acc[r][3];
        }
      }
      __syncthreads();
      // 104 j per half, 52 per wave; per round: 4 j x 16 nodes
      int jb = lo + w * 52;
      int node = lane & 15;
      int jo = lane >> 4;
      for (int jj = 0; jj < 52; jj += 4) {
        int j = jb + jj + jo;
        pBT[(size_t)j * NODES + row0 + node] = smem[node * TSTR + (j - lo)];
      }
    }
  } else {
    int ab = blk - 2048;           // b*16 + a
    int b = ab >> 4;
    int node = b * N_ + loc[ab];
    float* xr = smem;
    for (int i = t; i < MID_; i += 128) xr[i] = xc[(size_t)node * MID_ + i];
    __syncthreads();
    for (int j = t; j < MID_; j += 128) {
      float acc = 0.f;
      for (int i = 0; i < MID_; i++) acc = fmaf(xr[i], W1[i * MID_ + j], acc);
      pA[ab * MID_ + j] = acc;
    }
  }
}

// ---------------- fin: one block per feature j — BN finalize + vaT + wpack (64 sub-blocks/b) ----------------
__global__ __launch_bounds__(256) void k_fin(const float* __restrict__ SBp,
                                             const float* __restrict__ pA,
                                             const float* __restrict__ cu,
                                             const float* __restrict__ base,
                                             const float* __restrict__ d1row,
                                             const float* __restrict__ c2row,
                                             const int* __restrict__ loc,
                                             const float* __restrict__ bng,
                                             const float* __restrict__ bnb,
                                             const float* __restrict__ W2,
                                             float* __restrict__ vaT,
                                             float* __restrict__ wpack4) {
  __shared__ float utmp[1536 + 192];
  __shared__ float redm[4];
  __shared__ float reds[4];
  __shared__ float bcast[2];
  int t = threadIdx.x, lane = t & 63, w = t >> 6;
  int j = blockIdx.x;
  float cuj = cu[j], bj = base[j];
  int bb = t >> 3, ii = t & 7;
  float q1 = 0, q2 = 0, q3 = 0, t1 = 0, t2 = 0, t3 = 0;
#pragma unroll
  for (int i = ii * 8; i < ii * 8 + 8; i++) {
    const float* sp = SBp + (size_t)(bb * 64 + i) * 624;
    q1 += sp[j];
    q2 += sp[208 + j];
    q3 += sp[416 + j];
  }
#pragma unroll
  for (int a = ii * 2; a < ii * 2 + 2; a++) {
    int r = bb * 16 + a;
    float pa = pA[r * MID_ + j] + bj;
    t1 += pa;
    t2 = fmaf(pa, pa, t2);
    t3 = fmaf(pa, d1row[loc[r]], t3);
  }
  utmp[0 * 256 + t] = q1;
  utmp[1 * 256 + t] = q2;
  utmp[2 * 256 + t] = q3;
  utmp[3 * 256 + t] = t1;
  utmp[4 * 256 + t] = t2;
  utmp[5 * 256 + t] = t3;
  float p1 = 0.f, p2 = 0.f;
#pragma unroll
  for (int r = t * 2; r < t * 2 + 2; r++) {
    int l = loc[r];
    p1 += d1row[l];
    p2 += c2row[l];
  }
#pragma unroll
  for (int o = 32; o > 0; o >>= 1) { p1 += __shfl_xor(p1, o); p2 += __shfl_xor(p2, o); }
  if (lane == 0) { redm[w] = p1; reds[w] = p2; }
  __syncthreads();
  if (t < 192) {
    int s = t >> 5, b32 = t & 31;
    float ssum = 0.f;
#pragma unroll
    for (int i = 0; i < 8; i++) ssum += utmp[s * 256 + b32 * 8 + i];
    utmp[1536 + s * 32 + b32] = ssum;
  }
  __syncthreads();
  if (t == 0) {
    float Sc1 = (redm[0] + redm[1]) + (redm[2] + redm[3]);
    float Sc2 = (reds[0] + reds[1]) + (reds[2] + reds[3]);
    double T1 = 0, T2 = 0, T3 = 0, cross = 0, sp1 = 0, sp2 = 0, spe = 0;
    for (int b = 0; b < 32; b++) {
      float sq1 = utmp[1536 + 0 * 32 + b];
      float sq2 = utmp[1536 + 1 * 32 + b];
      float sq3 = utmp[1536 + 2 * 32 + b];
      float pt1 = utmp[1536 + 3 * 32 + b];
      float pt2 = utmp[1536 + 4 * 32 + b];
      float pt3 = utmp[1536 + 5 * 32 + b];
      T1 += pt1; T2 += pt2; T3 += pt3;
      cross += (double)pt1 * sq1;
      sp1 += sq1; sp2 += sq2; spe += sq3;
    }
    double s1 = 1024.0 * T1 + 16.0 * sp1 + (double)cuj * Sc1;
    double s2 = 1024.0 * T2 + 16.0 * sp2 + (double)cuj * cuj * Sc2 +
                2.0 * (cross + (double)cuj * (T3 + spe));
    double mu = s1 * (1.0 / (double)ROWS);
    double var = s2 * (1.0 / (double)ROWS) - mu * mu;
    float sc = (float)(1.0 / sqrt(var + 1e-5)) * bng[j];
    float sh = bnb[j] - (float)mu * sc;
    bcast[0] = sc;
    bcast[1] = sh;
    wpack4[4 * j + 0] = sc;
    wpack4[4 * j + 1] = cuj * sc;
    wpack4[4 * j + 2] = W2[j];
    wpack4[4 * j + 3] = 0.f;
  }
  __syncthreads();
  float sc = bcast[0], sh = bcast[1];
#pragma unroll
  for (int r = t * 2; r < t * 2 + 2; r++) {
    int b = r >> 4, a = r & 15;
    float pa = pA[r * MID_ + j] + bj;
    vaT[((size_t)b * MID_ + j) * 16 + a] = pa * sc + sh;
  }
}

// ---------------- logits: read pBT (coalesced), vaT via LDS; + softmax partials ----------------
__global__ __launch_bounds__(256) void k_logits(const float* __restrict__ pBT,
                                                const float* __restrict__ vaT,
                                                const float* __restrict__ wpack4,
                                                const float* __restrict__ dist,
                                                const int* __restrict__ loc,
                                                const int* __restrict__ mask,
                                                const float* __restrict__ b2,
                                                float* __restrict__ lg,
                                                float2* __restrict__ Psm) {
  __shared__ float vaS[MID_ * 16];
  __shared__ float accL[4][8][64];
  __shared__ int loc_s[16];
  __shared__ float redm[4];
  __shared__ float reds[4];
  int t = threadIdx.x, lane = t & 63;
  int w = __builtin_amdgcn_readfirstlane(t >> 6);
  int b = blockIdx.y, nt = blockIdx.x;
  int n0 = nt * 64;
  if (t < 16) loc_s[t] = loc[b * 16 + t];
  for (int i = t; i < MID_ * 16; i += 256) vaS[i] = vaT[(size_t)b * MID_ * 16 + i];
  __syncthreads();
  float c[16];
#pragma unroll
  for (int a = 0; a < 16; a++) c[a] = dist[(size_t)loc_s[a] * N_ + n0 + lane];
  float acc16[16];
#pragma unroll
  for (int a = 0; a < 16; a++) acc16[a] = 0.f;
  const float4* wp = (const float4*)wpack4;
  int ng = b * N_ + n0 + lane;
  int jb = w * 52;
#pragma unroll 4
  for (int jj = 0; jj < 52; jj++) {
    int j = jb + jj;
    float pbv = pBT[(size_t)j * NODES + ng];
    float4 wv = wp[j];
    float pbs = pbv * wv.x;
    const float* va = &vaS[j * 16];
#pragma unroll
    for (int a = 0; a < 16; a++) {
      float h = fmaf(c[a], wv.y, va[a] + pbs);
      h = fmaxf(h, 0.f);
      acc16[a] = fmaf(h, wv.z, acc16[a]);
    }
  }

  float b2v = b2[0];
  float sv[4];
  int ois[4];
  unsigned mk = 0;
#pragma unroll
  for (int half = 0; half < 2; half++) {
#pragma unroll
    for (int a8 = 0; a8 < 8; a8++) accL[t >> 6][a8][lane] = acc16[half * 8 + a8];
    __syncthreads();
#pragma unroll
    for (int p = 0; p < 2; p++) {
      int idx = p * 256 + t;
      int a8 = idx >> 6, nn = idx & 63;
      float s = (accL[0][a8][nn] + accL[1][a8][nn]) +
                (accL[2][a8][nn] + accL[3][a8][nn]) + b2v;
      int a = half * 8 + a8;
      int oi = b * AN_ + a * N_ + n0 + nn;
      int iv = half * 2 + p;
      bool m_ = mask[oi] != 0;
      sv[iv] = m_ ? s : -1e8f;
      ois[iv] = oi;
      mk |= (m_ ? 1u : 0u) << iv;
    }
    __syncthreads();
  }

  float mx = fmaxf(fmaxf(sv[0], sv[1]), fmaxf(sv[2], sv[3]));
#pragma unroll
  for (int o = 32; o > 0; o >>= 1) mx = fmaxf(mx, __shfl_xor(mx, o));
  if (lane == 0) redm[t >> 6] = mx;
  __syncthreads();
  mx = fmaxf(fmaxf(redm[0], redm[1]), fmaxf(redm[2], redm[3]));
  float ssum = 0.f;
#pragma unroll
  for (int iv = 0; iv < 4; iv++) {
    float pv = ((mk >> iv) & 1u) ? expf(sv[iv] - mx) : 0.f;
    lg[ois[iv]] = pv;
    ssum += pv;
  }
#pragma unroll
  for (int o = 32; o > 0; o >>= 1) ssum += __shfl_xor(ssum, o);
  if (lane == 0) reds[t >> 6] = ssum;
  __syncthreads();
  if (t == 0) Psm[b * 16 + nt] = make_float2(mx, (reds[0] + reds[1]) + (reds[2] + reds[3]));
}

// ---------------- sm2: combine 16 block-partials per batch, normalize ----------------
__global__ __launch_bounds__(256) void k_sm2(const float* __restrict__ lg,
                                             const float2* __restrict__ P,
                                             float* __restrict__ out) {
  __shared__ float scs[16];
  int b = blockIdx.y, x = blockIdx.x, t = threadIdx.x;
  float M = -3.0e38f;
  float2 pr[16];
#pragma unroll
  for (int k = 0; k < 16; k++) {
    pr[k] = P[b * 16 + k];
    M = fmaxf(M, pr[k].x);
  }
  float S = 0.f;
#pragma unroll
  for (int k = 0; k < 16; k++) S += pr[k].y * expf(pr[k].x - M);
  float inv = 1.0f / S;
  if (t < 16) scs[t] = expf(pr[t].x - M) * inv;
  __syncthreads();
  const float* lb = lg + b * AN_ + x * 2048;
  float* ob = out + b * AN_ + x * 2048;
#pragma unroll
  for (int k = 0; k < 8; k++) {
    int i = t + 256 * k;
    int n = (x * 2048 + i) & 1023;
    ob[i] = lb[i] * scs[n >> 6];
  }
}

extern "C" void kernel_launch(void* const* d_in, const int* in_sizes, int n_in,
                              void* d_out, int out_size, void* d_ws, size_t ws_size,
                              hipStream_t stream) {
  const float* gn = (const float*)d_in[0];
  const int* el = (const int*)d_in[1];
  const int* loc = (const int*)d_in[2];
  const int* mask = (const int*)d_in[3];
  const float* dist = (const float*)d_in[4];
  const float* c0W = (const float*)d_in[5];
  const float* c0b = (const float*)d_in[6];
  const float* c0g = (const float*)d_in[7];
  const float* c0be = (const float*)d_in[8];
  const float* c1W = (const float*)d_in[9];
  const float* c1b = (const float*)d_in[10];
  const float* c1g = (const float*)d_in[11];
  const float* c1be = (const float*)d_in[12];
  const float* c2W = (const float*)d_in[13];
  const float* c2b = (const float*)d_in[14];
  const float* c2g = (const float*)d_in[15];
  const float* c2be = (const float*)d_in[16];
  const float* eW = (const float*)d_in[17];
  const float* eb = (const float*)d_in[18];
  const float* W1 = (const float*)d_in[19];
  const float* b1 = (const float*)d_in[20];
  const float* bng = (const float*)d_in[21];
  const float* bnb = (const float*)d_in[22];
  const float* W2 = (const float*)d_in[23];
  const float* b2 = (const float*)d_in[24];
  float* out = (float*)d_out;

  char* p = (char*)d_ws;
  auto alloc = [&](size_t bytes) {
    char* r = p;
    p += (bytes + 255) & ~(size_t)255;
    return r;
  };
  int* counts = (int*)alloc((size_t)NODES * 4);
  int* rowptr = (int*)alloc((size_t)NODES * 4);
  int* ssrc = (int*)alloc((size_t)NEDGE * 4);
  float* xc = (float*)alloc((size_t)NODES * MID_ * 4);
  float* pBT = (float*)alloc((size_t)NODES * MID_ * 4);
  float* pA = (float*)alloc((size_t)512 * MID_ * 4);
  float* cu = (float*)alloc(256 * 4);
  float* base = (float*)alloc(256 * 4);
  float* d1row = (float*)alloc((size_t)N_ * 4);
  float* c2row = (float*)alloc((size_t)N_ * 4);
  float* e1 = (float*)alloc((size_t)B_ * N_ * 4);
  float* SBp = (float*)alloc((size_t)2048 * 624 * 4);
  float* vaT = (float*)alloc((size_t)B_ * MID_ * 16 * 4);
  float* wpack4 = (float*)alloc((size_t)MID_ * 4 * 4);
  float* lg = (float*)alloc((size_t)ROWS * 4);
  float2* Psm = (float2*)alloc((size_t)B_ * 16 * 8);

  k_front<<<321, 256, 0, stream>>>(el, dist, loc, W1, eW, eb, b1,
                                   rowptr, counts, ssrc, d1row, c2row, e1, cu, base);

  k_layer<16, true><<<1024, 256, 0, stream>>>(gn, FIN_, 0, xc, 16, rowptr, counts, ssrc, c0W, c0b, c0g, c0be);
  k_layer<64, false><<<1024, 256, 0, stream>>>(xc, MID_, 16, xc, 80, rowptr, counts, ssrc, c1W, c1b, c1g, c1be);
  k_layer<64, false><<<1024, 256, 0, stream>>>(xc, MID_, 80, xc, 144, rowptr, counts, ssrc, c2W, c2b, c2g, c2be);

  k_p1<<<2560, 128, 0, stream>>>(xc, W1, e1, loc, SBp, pBT, pA);
  k_fin<<<208, 256, 0, stream>>>(SBp, pA, cu, base, d1row, c2row, loc, bng, bnb, W2, vaT, wpack4);

  k_logits<<<dim3(16, 32), 256, 0, stream>>>(pBT, vaT, wpack4, dist, loc, mask, b2, lg, Psm);
  k_sm2<<<dim3(8, 32), 256, 0, stream>>>(lg, Psm, out);
}

// Round 17
// 266.114 us; speedup vs baseline: 1.0473x; 1.0473x over previous
//
#include <hip/hip_runtime.h>
#include <cstddef>

#define B_    32
#define N_    1024
#define E_    4096
#define A_    16
#define FIN_  16
#define H_    64
#define MID_  208
#define NODES (B_ * N_)      // 32768
#define NEDGE (B_ * E_)      // 131072
#define ROWS  (B_ * A_ * N_) // 524288
#define AN_   (A_ * N_)      // 16384

__device__ __forceinline__ float readlane_f(float v, int l) {
  return __uint_as_float(__builtin_amdgcn_readlane(__float_as_uint(v), l));
}

// ---------------- front: per-graph CSR in-block (LDS-staged ssrc) + d1 + csum + cu ----------------
__global__ __launch_bounds__(256) void k_front(const int* __restrict__ el,
                                               const float* __restrict__ dist,
                                               const int* __restrict__ loc,
                                               const float* __restrict__ W1,
                                               const float* __restrict__ eW,
                                               const float* __restrict__ eb,
                                               const float* __restrict__ b1,
                                               int* __restrict__ rowptr,
                                               int* __restrict__ counts,
                                               int* __restrict__ ssrc,
                                               float* __restrict__ d1row,
                                               float* __restrict__ c2row,
                                               float* __restrict__ e1,
                                               float* __restrict__ cu,
                                               float* __restrict__ base) {
  __shared__ int cnt[1024];
  __shared__ int cur[1024];
  __shared__ int part[256];
  __shared__ int ssrcS[4096];
  __shared__ int loc_s[16];
  int blk = blockIdx.x, t = threadIdx.x;
  if (blk < 32) {
    int b = blk;
    for (int i = t; i < 1024; i += 256) cnt[i] = 0;
    __syncthreads();
    const int* srcp = el + b * (2 * E_);
    const int* dstp = srcp + E_;
    for (int i = t; i < E_; i += 256) atomicAdd(&cnt[dstp[i]], 1);
    __syncthreads();
    int4 c4 = *(const int4*)&cnt[t * 4];
    int s = c4.x + c4.y + c4.z + c4.w;
    part[t] = s;
    __syncthreads();
    for (int off = 1; off < 256; off <<= 1) {
      int v = (t >= off) ? part[t - off] : 0;
      __syncthreads();
      part[t] += v;
      __syncthreads();
    }
    int prev = (t == 0) ? 0 : part[t - 1];
    int p0 = prev, p1 = p0 + c4.x, p2 = p1 + c4.y, p3 = p2 + c4.z;
    *(int4*)&rowptr[b * 1024 + t * 4] = make_int4(p0 + b * E_, p1 + b * E_, p2 + b * E_, p3 + b * E_);
    *(int4*)&counts[b * 1024 + t * 4] = c4;
    cur[t * 4 + 0] = p0;
    cur[t * 4 + 1] = p1;
    cur[t * 4 + 2] = p2;
    cur[t * 4 + 3] = p3;
    __syncthreads();
    for (int i = t; i < E_; i += 256) {
      int dl = dstp[i];
      int sl = srcp[i];
      int pos = atomicAdd(&cur[dl], 1);
      ssrcS[pos] = b * N_ + sl;
    }
    __syncthreads();
    for (int i = t; i < E_; i += 256) ssrc[b * E_ + i] = ssrcS[i];
  } else if (blk < 288) {
    int lane = t & 63, w = t >> 6;
    int r = (blk - 32) * 4 + w;
    const float* dr = dist + (size_t)r * N_;
    float s = 0.f, c2 = 0.f;
#pragma unroll
    for (int k = 0; k < 16; k++) {
      float v = dr[lane + 64 * k];
      s += v;
      c2 = fmaf(v, v, c2);
    }
#pragma unroll
    for (int o = 32; o > 0; o >>= 1) { s += __shfl_xor(s, o); c2 += __shfl_xor(c2, o); }
    if (lane == 0) { d1row[r] = s; c2row[r] = c2; }
  } else if (blk < 320) {
    int b = blk - 288;
    if (t < 16) loc_s[t] = loc[b * 16 + t];
    __syncthreads();
    float e4[4] = {0.f, 0.f, 0.f, 0.f};
    for (int a = 0; a < 16; a++) {
      const float* dr = dist + (size_t)loc_s[a] * N_;
#pragma unroll
      for (int k = 0; k < 4; k++) e4[k] += dr[t + 256 * k];
    }
#pragma unroll
    for (int k = 0; k < 4; k++) e1[b * N_ + t + 256 * k] = e4[k];
  } else {
    int j = t;
    if (j < MID_) {
      float c = 0.f, bs = 0.f;
      for (int k = 0; k < H_; k++) {
        float w = W1[(2 * MID_ + k) * MID_ + j];
        c = fmaf(eW[k], w, c);
        bs = fmaf(eb[k], w, bs);
      }
      cu[j] = c;
      base[j] = bs + b1[j];
    }
  }
}

// ---------------- GIN layer: XCD-swizzled blocks; wave per 8 nodes ----------------
// blk -> (xcd c = blk&7, k = blk>>3): graph = c*4 + (k>>5), node-block = k&31.
// All 32 blocks of a graph share one XCD -> graph's 832 KB xc slice stays in that L2.
template <int FINT, bool COPYIN>
__global__ __launch_bounds__(256) void k_layer(const float* __restrict__ xin, int xstride, int in_off,
                                               float* __restrict__ xc, int out_off,
                                               const int* __restrict__ rowptr,
                                               const int* __restrict__ counts,
                                               const int* __restrict__ ssrc,
                                               const float* __restrict__ W,
                                               const float* __restrict__ bias,
                                               const float* __restrict__ g,
                                               const float* __restrict__ beta) {
  int t = threadIdx.x, lane = t & 63, w = t >> 6;
  float Wcol[FINT];
#pragma unroll
  for (int f = 0; f < FINT; f++) Wcol[f] = W[f * 64 + lane];
  float bv = bias[lane], gv = g[lane], bev = beta[lane];
  constexpr int CH = 64 / FINT;
  int f = lane & (FINT - 1);
  int ch = (FINT == 64) ? 0 : (lane >> 4);
  int blk = blockIdx.x;
  int xcd = blk & 7, kk = blk >> 3;
  int graph = xcd * 4 + (kk >> 5);
  int nblk = kk & 31;
  int nbase = graph * N_ + nblk * 32 + w * 8;

  float agg[8];
#pragma unroll
  for (int nn = 0; nn < 8; nn++) {
    int node = nbase + nn;
    int r0 = rowptr[node];
    int deg = counts[node];
    float a0 = 0.f, a1 = 0.f, a2 = 0.f, a3 = 0.f;
    int e = ch;
    for (; e + 3 * CH < deg; e += 4 * CH) {
      int s0 = ssrc[r0 + e];
      int s1 = ssrc[r0 + e + CH];
      int s2 = ssrc[r0 + e + 2 * CH];
      int s3 = ssrc[r0 + e + 3 * CH];
      a0 += xin[(size_t)s0 * xstride + in_off + f];
      a1 += xin[(size_t)s1 * xstride + in_off + f];
      a2 += xin[(size_t)s2 * xstride + in_off + f];
      a3 += xin[(size_t)s3 * xstride + in_off + f];
    }
    for (; e < deg; e += CH) {
      int s = ssrc[r0 + e];
      a0 += xin[(size_t)s * xstride + in_off + f];
    }
    agg[nn] = (a0 + a1) + (a2 + a3);
  }

#pragma unroll
  for (int nn = 0; nn < 8; nn++) {
    int node = nbase + nn;
    float aggf = agg[nn];
    float y0 = bv, y1 = 0.f, y2 = 0.f, y3 = 0.f;
#pragma unroll
    for (int l = 0; l < 64; l += 4) {
      y0 = fmaf(readlane_f(aggf, l + 0), Wcol[(l + 0) & (FINT - 1)], y0);
      y1 = fmaf(readlane_f(aggf, l + 1), Wcol[(l + 1) & (FINT - 1)], y1);
      y2 = fmaf(readlane_f(aggf, l + 2), Wcol[(l + 2) & (FINT - 1)], y2);
      y3 = fmaf(readlane_f(aggf, l + 3), Wcol[(l + 3) & (FINT - 1)], y3);
    }
    float y = (y0 + y1) + (y2 + y3);
    float m = y;
#pragma unroll
    for (int o = 32; o > 0; o >>= 1) m += __shfl_xor(m, o);
    m *= (1.f / 64.f);
    float d = y - m;
    float vv = d * d;
#pragma unroll
    for (int o = 32; o > 0; o >>= 1) vv += __shfl_xor(vv, o);
    vv *= (1.f / 64.f);
    float outv = fmaxf(d * rsqrtf(vv + 1e-5f) * gv + bev, 0.f);
    xc[(size_t)node * MID_ + out_off + lane] = outv;
    if (COPYIN) {
      if (lane < FIN_) xc[(size_t)node * MID_ + lane] = xin[(size_t)node * FIN_ + lane];
    }
  }
}

// ---------------- LDS-free scalar-A GEMM core: wave = NR rows, lane = 4 j ----------------
template <int NR>
__device__ __forceinline__ void gemm_sc(const float* __restrict__ xc,
                                        const float* __restrict__ W1,
                                        int row0w, int j0, float acc[NR][4]) {
  const float* Bbase = W1 + (size_t)MID_ * MID_;
  const float* Arow = xc + (size_t)row0w * MID_;
#pragma unroll
  for (int r = 0; r < NR; r++)
#pragma unroll
    for (int q = 0; q < 4; q++) acc[r][q] = 0.f;

#pragma unroll 2
  for (int c = 0; c < 52; c++) {
    int k = c * 4;
    float4 a[NR];
    const float* ap = Arow + k;
#pragma unroll
    for (int r = 0; r < NR; r++) a[r] = *(const float4*)(ap + r * MID_);
#pragma unroll
    for (int q = 0; q < 4; q++) {
      float4 bq = *(const float4*)(Bbase + (size_t)(k + q) * MID_ + j0);
#pragma unroll
      for (int r = 0; r < NR; r++) {
        float ar = (q == 0) ? a[r].x : (q == 1) ? a[r].y : (q == 2) ? a[r].z : a[r].w;
        acc[r][0] = fmaf(ar, bq.x, acc[r][0]);
        acc[r][1] = fmaf(ar, bq.y, acc[r][1]);
        acc[r][2] = fmaf(ar, bq.z, acc[r][2]);
        acc[r][3] = fmaf(ar, bq.w, acc[r][3]);
      }
    }
  }
}

// ---------------- p1: 128-thread blocks. 0..2047: GEMM (2 waves x 8 rows) + stats + pBT; 2048..2559: pA ----------------
#define TSTR 105
__global__ __launch_bounds__(128) void k_p1(const float* __restrict__ xc,
                                            const float* __restrict__ W1,
                                            const float* __restrict__ e1,
                                            const int* __restrict__ loc,
                                            float* __restrict__ SBp,
                                            float* __restrict__ pBT,
                                            float* __restrict__ pA) {
  __shared__ float smem[1680];   // union: red[2*624] / accS[16*105] / xr[208]
  int t = threadIdx.x, lane = t & 63;
  int w = __builtin_amdgcn_readfirstlane(t >> 6);   // 0 or 1
  int blk = blockIdx.x;
  if (blk < 2048) {
    int row0 = blk * 16;
    int row0w = row0 + w * 8;
    int j0 = lane * 4;
    float acc[8][4];
    gemm_sc<8>(xc, W1, row0w, j0, acc);
    const float* ep = e1 + row0w;   // wave-uniform
    float4 e0 = *(const float4*)(ep);
    float4 e4 = *(const float4*)(ep + 4);
    float ev[8] = {e0.x, e0.y, e0.z, e0.w, e4.x, e4.y, e4.z, e4.w};
    if (j0 < MID_) {
      float s1[4] = {0, 0, 0, 0}, s2[4] = {0, 0, 0, 0}, se[4] = {0, 0, 0, 0};
#pragma unroll
      for (int r = 0; r < 8; r++) {
#pragma unroll
        for (int q = 0; q < 4; q++) {
          float v = acc[r][q];
          s1[q] += v;
          s2[q] = fmaf(v, v, s2[q]);
          se[q] = fmaf(v, ev[r], se[q]);
        }
      }
#pragma unroll
      for (int q = 0; q < 4; q++) {
        smem[w * 624 + j0 + q] = s1[q];
        smem[w * 624 + 208 + j0 + q] = s2[q];
        smem[w * 624 + 416 + j0 + q] = se[q];
      }
    }
    __syncthreads();
    for (int idx = t; idx < 624; idx += 128) {
      SBp[(size_t)blk * 624 + idx] = smem[idx] + smem[624 + idx];
    }
#pragma unroll
    for (int half = 0; half < 2; half++) {
      int lo = half * 104;
      __syncthreads();
      if (j0 >= lo && j0 < lo + 104) {
        int jc = j0 - lo;
#pragma unroll
        for (int r = 0; r < 8; r++) {
          int ba = (w * 8 + r) * TSTR + jc;
          smem[ba + 0] = acc[r][0];
          smem[ba + 1] = acc[r][1];
          smem[ba + 2] = acc[r][2];
          smem[ba + 3] = acc[r][3];
        }
      }
      __syncthreads();
      int jb = lo + w * 52;
      int node = lane & 15;
      int jo = lane >> 4;
      for (int jj = 0; jj < 52; jj += 4) {
        int j = jb + jj + jo;
        pBT[(size_t)j * NODES + row0 + node] = smem[node * TSTR + (j - lo)];
      }
    }
  } else {
    int ab = blk - 2048;           // b*16 + a
    int b = ab >> 4;
    int node = b * N_ + loc[ab];
    float* xr = smem;
    for (int i = t; i < MID_; i += 128) xr[i] = xc[(size_t)node * MID_ + i];
    __syncthreads();
    for (int j = t; j < MID_; j += 128) {
      float acc = 0.f;
      for (int i = 0; i < MID_; i++) acc = fmaf(xr[i], W1[i * MID_ + j], acc);
      pA[ab * MID_ + j] = acc;
    }
  }
}

// ---------------- fin: one block per feature j — BN finalize + vaT + wpack (64 sub-blocks/b) ----------------
__global__ __launch_bounds__(256) void k_fin(const float* __restrict__ SBp,
                                             const float* __restrict__ pA,
                                             const float* __restrict__ cu,
                                             const float* __restrict__ base,
                                             const float* __restrict__ d1row,
                                             const float* __restrict__ c2row,
                                             const int* __restrict__ loc,
                                             const float* __restrict__ bng,
                                             const float* __restrict__ bnb,
                                             const float* __restrict__ W2,
                                             float* __restrict__ vaT,
                                             float* __restrict__ wpack4) {
  __shared__ float utmp[1536 + 192];
  __shared__ float redm[4];
  __shared__ float reds[4];
  __shared__ float bcast[2];
  int t = threadIdx.x, lane = t & 63, w = t >> 6;
  int j = blockIdx.x;
  float cuj = cu[j], bj = base[j];
  int bb = t >> 3, ii = t & 7;
  float q1 = 0, q2 = 0, q3 = 0, t1 = 0, t2 = 0, t3 = 0;
#pragma unroll
  for (int i = ii * 8; i < ii * 8 + 8; i++) {
    const float* sp = SBp + (size_t)(bb * 64 + i) * 624;
    q1 += sp[j];
    q2 += sp[208 + j];
    q3 += sp[416 + j];
  }
#pragma unroll
  for (int a = ii * 2; a < ii * 2 + 2; a++) {
    int r = bb * 16 + a;
    float pa = pA[r * MID_ + j] + bj;
    t1 += pa;
    t2 = fmaf(pa, pa, t2);
    t3 = fmaf(pa, d1row[loc[r]], t3);
  }
  utmp[0 * 256 + t] = q1;
  utmp[1 * 256 + t] = q2;
  utmp[2 * 256 + t] = q3;
  utmp[3 * 256 + t] = t1;
  utmp[4 * 256 + t] = t2;
  utmp[5 * 256 + t] = t3;
  float p1 = 0.f, p2 = 0.f;
#pragma unroll
  for (int r = t * 2; r < t * 2 + 2; r++) {
    int l = loc[r];
    p1 += d1row[l];
    p2 += c2row[l];
  }
#pragma unroll
  for (int o = 32; o > 0; o >>= 1) { p1 += __shfl_xor(p1, o); p2 += __shfl_xor(p2, o); }
  if (lane == 0) { redm[w] = p1; reds[w] = p2; }
  __syncthreads();
  if (t < 192) {
    int s = t >> 5, b32 = t & 31;
    float ssum = 0.f;
#pragma unroll
    for (int i = 0; i < 8; i++) ssum += utmp[s * 256 + b32 * 8 + i];
    utmp[1536 + s * 32 + b32] = ssum;
  }
  __syncthreads();
  if (t == 0) {
    float Sc1 = (redm[0] + redm[1]) + (redm[2] + redm[3]);
    float Sc2 = (reds[0] + reds[1]) + (reds[2] + reds[3]);
    double T1 = 0, T2 = 0, T3 = 0, cross = 0, sp1 = 0, sp2 = 0, spe = 0;
    for (int b = 0; b < 32; b++) {
      float sq1 = utmp[1536 + 0 * 32 + b];
      float sq2 = utmp[1536 + 1 * 32 + b];
      float sq3 = utmp[1536 + 2 * 32 + b];
      float pt1 = utmp[1536 + 3 * 32 + b];
      float pt2 = utmp[1536 + 4 * 32 + b];
      float pt3 = utmp[1536 + 5 * 32 + b];
      T1 += pt1; T2 += pt2; T3 += pt3;
      cross += (double)pt1 * sq1;
      sp1 += sq1; sp2 += sq2; spe += sq3;
    }
    double s1 = 1024.0 * T1 + 16.0 * sp1 + (double)cuj * Sc1;
    double s2 = 1024.0 * T2 + 16.0 * sp2 + (double)cuj * cuj * Sc2 +
                2.0 * (cross + (double)cuj * (T3 + spe));
    double mu = s1 * (1.0 / (double)ROWS);
    double var = s2 * (1.0 / (double)ROWS) - mu * mu;
    float sc = (float)(1.0 / sqrt(var + 1e-5)) * bng[j];
    float sh = bnb[j] - (float)mu * sc;
    bcast[0] = sc;
    bcast[1] = sh;
    wpack4[4 * j + 0] = sc;
    wpack4[4 * j + 1] = cuj * sc;
    wpack4[4 * j + 2] = W2[j];
    wpack4[4 * j + 3] = 0.f;
  }
  __syncthreads();
  float sc = bcast[0], sh = bcast[1];
#pragma unroll
  for (int r = t * 2; r < t * 2 + 2; r++) {
    int b = r >> 4, a = r & 15;
    float pa = pA[r * MID_ + j] + bj;
    vaT[((size_t)b * MID_ + j) * 16 + a] = pa * sc + sh;
  }
}

// ---------------- logits: read pBT (coalesced), vaT via LDS; + softmax partials ----------------
__global__ __launch_bounds__(256) void k_logits(const float* __restrict__ pBT,
                                                const float* __restrict__ vaT,
                                                const float* __restrict__ wpack4,
                                                const float* __restrict__ dist,
                                                const int* __restrict__ loc,
                                                const int* __restrict__ mask,
                                                const float* __restrict__ b2,
                                                float* __restrict__ lg,
                                                float2* __restrict__ Psm) {
  __shared__ float vaS[MID_ * 16];
  __shared__ float accL[4][8][64];
  __shared__ int loc_s[16];
  __shared__ float redm[4];
  __shared__ float reds[4];
  int t = threadIdx.x, lane = t & 63;
  int w = __builtin_amdgcn_readfirstlane(t >> 6);
  int b = blockIdx.y, nt = blockIdx.x;
  int n0 = nt * 64;
  if (t < 16) loc_s[t] = loc[b * 16 + t];
  for (int i = t; i < MID_ * 16; i += 256) vaS[i] = vaT[(size_t)b * MID_ * 16 + i];
  __syncthreads();
  float c[16];
#pragma unroll
  for (int a = 0; a < 16; a++) c[a] = dist[(size_t)loc_s[a] * N_ + n0 + lane];
  float acc16[16];
#pragma unroll
  for (int a = 0; a < 16; a++) acc16[a] = 0.f;
  const float4* wp = (const float4*)wpack4;
  int ng = b * N_ + n0 + lane;
  int jb = w * 52;
#pragma unroll 4
  for (int jj = 0; jj < 52; jj++) {
    int j = jb + jj;
    float pbv = pBT[(size_t)j * NODES + ng];
    float4 wv = wp[j];
    float pbs = pbv * wv.x;
    const float* va = &vaS[j * 16];
#pragma unroll
    for (int a = 0; a < 16; a++) {
      float h = fmaf(c[a], wv.y, va[a] + pbs);
      h = fmaxf(h, 0.f);
      acc16[a] = fmaf(h, wv.z, acc16[a]);
    }
  }

  float b2v = b2[0];
  float sv[4];
  int ois[4];
  unsigned mk = 0;
#pragma unroll
  for (int half = 0; half < 2; half++) {
#pragma unroll
    for (int a8 = 0; a8 < 8; a8++) accL[t >> 6][a8][lane] = acc16[half * 8 + a8];
    __syncthreads();
#pragma unroll
    for (int p = 0; p < 2; p++) {
      int idx = p * 256 + t;
      int a8 = idx >> 6, nn = idx & 63;
      float s = (accL[0][a8][nn] + accL[1][a8][nn]) +
                (accL[2][a8][nn] + accL[3][a8][nn]) + b2v;
      int a = half * 8 + a8;
      int oi = b * AN_ + a * N_ + n0 + nn;
      int iv = half * 2 + p;
      bool m_ = mask[oi] != 0;
      sv[iv] = m_ ? s : -1e8f;
      ois[iv] = oi;
      mk |= (m_ ? 1u : 0u) << iv;
    }
    __syncthreads();
  }

  float mx = fmaxf(fmaxf(sv[0], sv[1]), fmaxf(sv[2], sv[3]));
#pragma unroll
  for (int o = 32; o > 0; o >>= 1) mx = fmaxf(mx, __shfl_xor(mx, o));
  if (lane == 0) redm[t >> 6] = mx;
  __syncthreads();
  mx = fmaxf(fmaxf(redm[0], redm[1]), fmaxf(redm[2], redm[3]));
  float ssum = 0.f;
#pragma unroll
  for (int iv = 0; iv < 4; iv++) {
    float pv = ((mk >> iv) & 1u) ? expf(sv[iv] - mx) : 0.f;
    lg[ois[iv]] = pv;
    ssum += pv;
  }
#pragma unroll
  for (int o = 32; o > 0; o >>= 1) ssum += __shfl_xor(ssum, o);
  if (lane == 0) reds[t >> 6] = ssum;
  __syncthreads();
  if (t == 0) Psm[b * 16 + nt] = make_float2(mx, (reds[0] + reds[1]) + (reds[2] + reds[3]));
}

// ---------------- sm2: combine 16 block-partials per batch, normalize ----------------
__global__ __launch_bounds__(256) void k_sm2(const float* __restrict__ lg,
                                             const float2* __restrict__ P,
                                             float* __restrict__ out) {
  __shared__ float scs[16];
  int b = blockIdx.y, x = blockIdx.x, t = threadIdx.x;
  float M = -3.0e38f;
  float2 pr[16];
#pragma unroll
  for (int k = 0; k < 16; k++) {
    pr[k] = P[b * 16 + k];
    M = fmaxf(M, pr[k].x);
  }
  float S = 0.f;
#pragma unroll
  for (int k = 0; k < 16; k++) S += pr[k].y * expf(pr[k].x - M);
  float inv = 1.0f / S;
  if (t < 16) scs[t] = expf(pr[t].x - M) * inv;
  __syncthreads();
  const float* lb = lg + b * AN_ + x * 2048;
  float* ob = out + b * AN_ + x * 2048;
#pragma unroll
  for (int k = 0; k < 8; k++) {
    int i = t + 256 * k;
    int n = (x * 2048 + i) & 1023;
    ob[i] = lb[i] * scs[n >> 6];
  }
}

extern "C" void kernel_launch(void* const* d_in, const int* in_sizes, int n_in,
                              void* d_out, int out_size, void* d_ws, size_t ws_size,
                              hipStream_t stream) {
  const float* gn = (const float*)d_in[0];
  const int* el = (const int*)d_in[1];
  const int* loc = (const int*)d_in[2];
  const int* mask = (const int*)d_in[3];
  const float* dist = (const float*)d_in[4];
  const float* c0W = (const float*)d_in[5];
  const float* c0b = (const float*)d_in[6];
  const float* c0g = (const float*)d_in[7];
  const float* c0be = (const float*)d_in[8];
  const float* c1W = (const float*)d_in[9];
  const float* c1b = (const float*)d_in[10];
  const float* c1g = (const float*)d_in[11];
  const float* c1be = (const float*)d_in[12];
  const float* c2W = (const float*)d_in[13];
  const float* c2b = (const float*)d_in[14];
  const float* c2g = (const float*)d_in[15];
  const float* c2be = (const float*)d_in[16];
  const float* eW = (const float*)d_in[17];
  const float* eb = (const float*)d_in[18];
  const float* W1 = (const float*)d_in[19];
  const float* b1 = (const float*)d_in[20];
  const float* bng = (const float*)d_in[21];
  const float* bnb = (const float*)d_in[22];
  const float* W2 = (const float*)d_in[23];
  const float* b2 = (const float*)d_in[24];
  float* out = (float*)d_out;

  char* p = (char*)d_ws;
  auto alloc = [&](size_t bytes) {
    char* r = p;
    p += (bytes + 255) & ~(size_t)255;
    return r;
  };
  int* counts = (int*)alloc((size_t)NODES * 4);
  int* rowptr = (int*)alloc((size_t)NODES * 4);
  int* ssrc = (int*)alloc((size_t)NEDGE * 4);
  float* xc = (float*)alloc((size_t)NODES * MID_ * 4);
  float* pBT = (float*)alloc((size_t)NODES * MID_ * 4);
  float* pA = (float*)alloc((size_t)512 * MID_ * 4);
  float* cu = (float*)alloc(256 * 4);
  float* base = (float*)alloc(256 * 4);
  float* d1row = (float*)alloc((size_t)N_ * 4);
  float* c2row = (float*)alloc((size_t)N_ * 4);
  float* e1 = (float*)alloc((size_t)B_ * N_ * 4);
  float* SBp = (float*)alloc((size_t)2048 * 624 * 4);
  float* vaT = (float*)alloc((size_t)B_ * MID_ * 16 * 4);
  float* wpack4 = (float*)alloc((size_t)MID_ * 4 * 4);
  float* lg = (float*)alloc((size_t)ROWS * 4);
  float2* Psm = (float2*)alloc((size_t)B_ * 16 * 8);

  k_front<<<321, 256, 0, stream>>>(el, dist, loc, W1, eW, eb, b1,
                                   rowptr, counts, ssrc, d1row, c2row, e1, cu, base);

  k_layer<16, true><<<1024, 256, 0, stream>>>(gn, FIN_, 0, xc, 16, rowptr, counts, ssrc, c0W, c0b, c0g, c0be);
  k_layer<64, false><<<1024, 256, 0, stream>>>(xc, MID_, 16, xc, 80, rowptr, counts, ssrc, c1W, c1b, c1g, c1be);
  k_layer<64, false><<<1024, 256, 0, stream>>>(xc, MID_, 80, xc, 144, rowptr, counts, ssrc, c2W, c2b, c2g, c2be);

  k_p1<<<2560, 128, 0, stream>>>(xc, W1, e1, loc, SBp, pBT, pA);
  k_fin<<<208, 256, 0, stream>>>(SBp, pA, cu, base, d1row, c2row, loc, bng, bnb, W2, vaT, wpack4);

  k_logits<<<dim3(16, 32), 256, 0, stream>>>(pBT, vaT, wpack4, dist, loc, mask, b2, lg, Psm);
  k_sm2<<<dim3(8, 32), 256, 0, stream>>>(lg, Psm, out);
}